// Round 11
// baseline (87.737 us; speedup 1.0000x reference)
//
#include <hip/hip_runtime.h>

// Fully-fused cascaded-biquad IIR (DF2T) via linear state-space chunking.
// ONE kernel, block = one batch row (512 blocks x 512 threads = 512 chunks).
// R11: ALL global access 128B-line-dense. Reads staged per-WAVE through an
// 8KB LDS half-tile (64 chunks x 8 float4) with wave-local s_waitcnt sync;
// writes use the same in-place transpose (R9/R10-validated). Scan uses a
// W0/W1 double buffer (1 barrier per level). Ms powers built redundantly
// by every wave via __shfl. No workspace.

namespace {
constexpr int NS     = 4;
constexpr int BATCH  = 512;
constexpr int TLEN   = 32768;      // 2^15
constexpr int NSTATE = 8;
constexpr int P      = 512;        // chunks per batch = threads per block
constexpr int L      = TLEN / P;   // 64 steps per chunk
constexpr int LQ     = L / 4;      // 16 float4 per chunk
constexpr int LOG2P  = 9;
constexpr int LOG2L  = 6;
}

#define LGKM0 do { asm volatile("s_waitcnt lgkmcnt(0)" ::: "memory"); \
                   __builtin_amdgcn_sched_barrier(0); } while (0)

__device__ __forceinline__ void load_coefs(const float* __restrict__ bc,
                                           const float* __restrict__ ac,
                                           float b0[NS], float b1[NS], float b2[NS],
                                           float a1[NS], float a2[NS]) {
#pragma unroll
  for (int k = 0; k < NS; ++k) {
    b0[k] = bc[3 * k];
    b1[k] = bc[3 * k + 1];
    b2[k] = bc[3 * k + 2];
    a1[k] = ac[2 * k];
    a2[k] = ac[2 * k + 1];
  }
}

// One time-step through the 4-section cascade (matches reference exactly).
__device__ __forceinline__ float step_cascade(float sig,
                                              const float b0[NS], const float b1[NS],
                                              const float b2[NS], const float a1[NS],
                                              const float a2[NS],
                                              float s1[NS], float s2[NS]) {
#pragma unroll
  for (int k = 0; k < NS; ++k) {
    float y = fmaf(b0[k], sig, s1[k]);
    s1[k]   = fmaf(-a1[k], y, fmaf(b1[k], sig, s2[k]));
    s2[k]   = fmaf(-a2[k], y, b2[k] * sig);
    sig = y;
  }
  return sig;
}

#define CO b0, b1, b2, a1, a2

__device__ __forceinline__ void adv4(const float4 u,
                                     const float b0[NS], const float b1[NS],
                                     const float b2[NS], const float a1[NS],
                                     const float a2[NS], float s1[NS], float s2[NS]) {
  (void)step_cascade(u.x, CO, s1, s2);
  (void)step_cascade(u.y, CO, s1, s2);
  (void)step_cascade(u.z, CO, s1, s2);
  (void)step_cascade(u.w, CO, s1, s2);
}

__device__ __forceinline__ float4 out4(const float4 u,
                                       const float b0[NS], const float b1[NS],
                                       const float b2[NS], const float a1[NS],
                                       const float a2[NS], float s1[NS], float s2[NS]) {
  float4 y;
  y.x = step_cascade(u.x, CO, s1, s2);
  y.y = step_cascade(u.y, CO, s1, s2);
  y.z = step_cascade(u.z, CO, s1, s2);
  y.w = step_cascade(u.w, CO, s1, s2);
  return y;
}

__global__ __launch_bounds__(P) void k_fused(const float* __restrict__ x,
                                             const float* __restrict__ bc,
                                             const float* __restrict__ ac,
                                             float* __restrict__ out) {
  // 64 KiB arena. Phases 1/4: wave wv owns float4 [wv*512, wv*512+512).
  // Scan: Msf = floats [0,576), W0 = [576,5184), W1 = [5184,9792).
  __shared__ float4 arena[4096];
  float* Msf = reinterpret_cast<float*>(arena);
  float* W0f = reinterpret_cast<float*>(arena) + 576;
  float* W1f = reinterpret_cast<float*>(arena) + 5184;

  const int t    = threadIdx.x;
  const int lane = t & 63;
  const int wv   = t >> 6;
  float4* __restrict__ Lb = arena + (wv << 9);  // this wave's 8KB region

  float b0[NS], b1[NS], b2[NS], a1[NS], a2[NS];
  load_coefs(bc, ac, b0, b1, b2, a1, a2);

  // Staging maps (128B-dense): instr j covers chunks 8j..8j+7 of this wave,
  // 8 consecutive lanes = one full 128B line of one chunk.
  const int m   = lane & 7;
  const int g0  = (wv * 64 + (lane >> 3)) * LQ + m;            // + ht*8 + 128j
  const int ls0 = (lane >> 3) * 8 + (m ^ ((lane >> 3) & 7));   // + 64j
  const int rs0 = lane * 8;                                    // + (q ^ (lane&7))

  const float4* __restrict__ gx =
      reinterpret_cast<const float4*>(x) + (size_t)blockIdx.x * (P * LQ);
  float4* __restrict__ gy =
      reinterpret_cast<float4*>(out) + (size_t)blockIdx.x * (P * LQ);

  // ================= phase 1: chunk final state from zero =================
  float4 tmp[8];
#pragma unroll
  for (int j = 0; j < 8; ++j) tmp[j] = gx[g0 + 128 * j];          // HT0
  float s1[NS] = {0.f, 0.f, 0.f, 0.f};
  float s2[NS] = {0.f, 0.f, 0.f, 0.f};
#pragma unroll
  for (int j = 0; j < 8; ++j) Lb[ls0 + 64 * j] = tmp[j];
#pragma unroll
  for (int j = 0; j < 8; ++j) tmp[j] = gx[g0 + 8 + 128 * j];      // HT1 prefetch
  LGKM0;
#pragma unroll
  for (int q = 0; q < 8; ++q) adv4(Lb[rs0 + (q ^ (lane & 7))], CO, s1, s2);
  LGKM0;  // WAR: reads done before region overwrite
#pragma unroll
  for (int j = 0; j < 8; ++j) Lb[ls0 + 64 * j] = tmp[j];
  LGKM0;
#pragma unroll
  for (int q = 0; q < 8; ++q) adv4(Lb[rs0 + (q ^ (lane & 7))], CO, s1, s2);

  float w[NSTATE];
#pragma unroll
  for (int k = 0; k < NS; ++k) { w[2 * k] = s1[k]; w[2 * k + 1] = s2[k]; }

  __syncthreads();  // all phase-1 LDS traffic done before arena repurpose

  // ===== Ms[d] = (A^L)^(2^d): every wave computes via __shfl, wave 0 stores =====
  {
    const int r = lane >> 3, cc = lane & 7;
    float p1[NS] = {0.f, 0.f, 0.f, 0.f};
    float p2[NS] = {0.f, 0.f, 0.f, 0.f};
    if (cc & 1) p2[cc >> 1] = 1.0f; else p1[cc >> 1] = 1.0f;
    (void)step_cascade(0.0f, CO, p1, p2);
    float mm = (r & 1) ? p2[r >> 1] : p1[r >> 1];  // A element (r,cc)
    for (int it = 0; it < LOG2L + LOG2P - 1; ++it) {
      float acc = 0.0f;
#pragma unroll
      for (int k = 0; k < NSTATE; ++k)
        acc = fmaf(__shfl(mm, r * 8 + k), __shfl(mm, k * 8 + cc), acc);
      mm = acc;
      asm volatile("" :: "v"(mm));  // keep all waves computing (no sink to wave 0)
      if (t < 64 && it >= LOG2L - 1) Msf[(it - (LOG2L - 1)) * 64 + t] = mm;
    }
  }

  // ================= phase 2: Kogge-Stone scan (W0/W1 dbuf) =================
#pragma unroll
  for (int r = 0; r < NSTATE; ++r) W0f[t * 9 + r] = w[r];
  __syncthreads();  // W0 + Ms ready
#pragma unroll
  for (int d = 0; d < LOG2P; ++d) {
    const float* Ws = (d & 1) ? W1f : W0f;
    float* Wd       = (d & 1) ? W0f : W1f;
    if (t >= (1 << d)) {
      const int src = (t - (1 << d)) * 9;
      float prev[NSTATE];
#pragma unroll
      for (int r = 0; r < NSTATE; ++r) prev[r] = Ws[src + r];
#pragma unroll
      for (int r = 0; r < NSTATE; ++r) {
        float acc = w[r];
#pragma unroll
        for (int k = 0; k < NSTATE; ++k)
          acc = fmaf(Msf[d * 64 + r * 8 + k], prev[k], acc);  // uniform: broadcast
        w[r] = acc;
      }
    }
#pragma unroll
    for (int r = 0; r < NSTATE; ++r) Wd[t * 9 + r] = w[r];
    __syncthreads();
  }

  // exclusive shift: final inclusive values are in W1 (d=8 wrote W1)
  {
    const int src = (t == 0 ? 0 : t - 1) * 9;
#pragma unroll
    for (int k = 0; k < NS; ++k) {
      s1[k] = (t == 0) ? 0.0f : W1f[src + 2 * k];
      s2[k] = (t == 0) ? 0.0f : W1f[src + 2 * k + 1];
    }
  }

  // issue phase-4 HT0 loads now (HBM latency hides under the barrier)
#pragma unroll
  for (int j = 0; j < 8; ++j) tmp[j] = gx[g0 + 128 * j];
  __syncthreads();  // scan reads done before arena overwrite

  // ================= phase 4: replay from exact init =================
  // HT0: stage -> in-place compute -> dense store
#pragma unroll
  for (int j = 0; j < 8; ++j) Lb[ls0 + 64 * j] = tmp[j];
#pragma unroll
  for (int j = 0; j < 8; ++j) tmp[j] = gx[g0 + 8 + 128 * j];  // HT1 prefetch
  LGKM0;
#pragma unroll
  for (int q = 0; q < 8; ++q) {
    const int s = rs0 + (q ^ (lane & 7));
    Lb[s] = out4(Lb[s], CO, s1, s2);  // in-place: own slots only
  }
  LGKM0;
#pragma unroll
  for (int j = 0; j < 8; ++j) gy[g0 + 128 * j] = Lb[ls0 + 64 * j];
  LGKM0;  // WAR: store-side ds_reads done before HT1 staging
  // HT1
#pragma unroll
  for (int j = 0; j < 8; ++j) Lb[ls0 + 64 * j] = tmp[j];
  LGKM0;
#pragma unroll
  for (int q = 0; q < 8; ++q) {
    const int s = rs0 + (q ^ (lane & 7));
    Lb[s] = out4(Lb[s], CO, s1, s2);
  }
  LGKM0;
#pragma unroll
  for (int j = 0; j < 8; ++j) gy[g0 + 8 + 128 * j] = Lb[ls0 + 64 * j];
}

extern "C" void kernel_launch(void* const* d_in, const int* in_sizes, int n_in,
                              void* d_out, int out_size, void* d_ws, size_t ws_size,
                              hipStream_t stream) {
  const float* x  = (const float*)d_in[0];  // (B, T, 1)
  const float* bc = (const float*)d_in[1];  // (NS, 3)
  const float* ac = (const float*)d_in[2];  // (NS, 2)
  float* out = (float*)d_out;               // (B, T, 1)

  k_fused<<<BATCH, P, 0, stream>>>(x, bc, ac, out);
}

// Round 12
// 51.065 us; speedup vs baseline: 1.7182x; 1.7182x over previous
//
#include <hip/hip_runtime.h>

// Fully-fused cascaded-biquad IIR (DF2T) via linear state-space chunking.
// R12: x RESIDENT IN LDS (148.3KB dynamic, gfx950 has 160KB/CU).
//   stage-in once (global_load_lds, linear dest + pre-swizzled source)
//   -> P1 chunk states from LDS -> Kogge-Stone scan (R10 code)
//   -> P4 replay from LDS in-place (y over x) -> dense linear store-out.
// Fallback: R10's 64KB-static kernel if the big-LDS launch is rejected.

namespace {
constexpr int NS     = 4;
constexpr int BATCH  = 512;
constexpr int TLEN   = 32768;      // 2^15
constexpr int NSTATE = 8;
constexpr int P      = 512;        // chunks per batch = threads per block
constexpr int L      = TLEN / P;   // 64 steps per chunk
constexpr int LQ     = L / 4;      // 16 float4 per chunk
constexpr int LOG2P  = 9;
constexpr int LOG2L  = 6;
constexpr int XF4    = P * LQ;     // 8192 float4 = 128KB of x per block
constexpr size_t DYN_LDS = (size_t)XF4 * 16 + (576 + 4608) * 4;  // 151808 B
}

#if defined(__has_builtin)
#  if __has_builtin(__builtin_amdgcn_global_load_lds)
#    define USE_GLL 1
#  endif
#endif
#ifndef USE_GLL
#  define USE_GLL 0
#endif

__device__ __forceinline__ void load_coefs(const float* __restrict__ bc,
                                           const float* __restrict__ ac,
                                           float b0[NS], float b1[NS], float b2[NS],
                                           float a1[NS], float a2[NS]) {
#pragma unroll
  for (int k = 0; k < NS; ++k) {
    b0[k] = bc[3 * k];
    b1[k] = bc[3 * k + 1];
    b2[k] = bc[3 * k + 2];
    a1[k] = ac[2 * k];
    a2[k] = ac[2 * k + 1];
  }
}

__device__ __forceinline__ float step_cascade(float sig,
                                              const float b0[NS], const float b1[NS],
                                              const float b2[NS], const float a1[NS],
                                              const float a2[NS],
                                              float s1[NS], float s2[NS]) {
#pragma unroll
  for (int k = 0; k < NS; ++k) {
    float y = fmaf(b0[k], sig, s1[k]);
    s1[k]   = fmaf(-a1[k], y, fmaf(b1[k], sig, s2[k]));
    s2[k]   = fmaf(-a2[k], y, b2[k] * sig);
    sig = y;
  }
  return sig;
}

#define CO b0, b1, b2, a1, a2

__device__ __forceinline__ void adv4(const float4 u,
                                     const float b0[NS], const float b1[NS],
                                     const float b2[NS], const float a1[NS],
                                     const float a2[NS], float s1[NS], float s2[NS]) {
  (void)step_cascade(u.x, CO, s1, s2);
  (void)step_cascade(u.y, CO, s1, s2);
  (void)step_cascade(u.z, CO, s1, s2);
  (void)step_cascade(u.w, CO, s1, s2);
}

__device__ __forceinline__ float4 out4(const float4 u,
                                       const float b0[NS], const float b1[NS],
                                       const float b2[NS], const float a1[NS],
                                       const float a2[NS], float s1[NS], float s2[NS]) {
  float4 y;
  y.x = step_cascade(u.x, CO, s1, s2);
  y.y = step_cascade(u.y, CO, s1, s2);
  y.z = step_cascade(u.z, CO, s1, s2);
  y.w = step_cascade(u.w, CO, s1, s2);
  return y;
}

// ===========================================================================
// R12 kernel: x resident in dynamic LDS.
// Wave wv owns 16KB region arena[wv*1024 .. +1024) = its 64 chunks x 16 f4.
// Slot map: slot(cc,q) = cc*16 + (q ^ (cc&15))  (cc = chunk within wave).
__global__ __launch_bounds__(P, 2) void k_fused_res(const float* __restrict__ x,
                                                    const float* __restrict__ bc,
                                                    const float* __restrict__ ac,
                                                    float* __restrict__ out) {
  extern __shared__ float4 arena[];
  float* Msf = reinterpret_cast<float*>(arena + XF4);  // [LOG2P][64]
  float* Wf  = Msf + 576;                              // [P][9]

  const int t    = threadIdx.x;
  const int lane = t & 63;
  const int wv   = t >> 6;
  float4* __restrict__ Lb = arena + (wv << 10);  // this wave's 16KB

  float b0[NS], b1[NS], b2[NS], a1[NS], a2[NS];
  load_coefs(bc, ac, b0, b1, b2, a1, a2);

  const float4* __restrict__ gx = reinterpret_cast<const float4*>(x) +
      (size_t)blockIdx.x * XF4 + ((size_t)wv << 10);
  float4* __restrict__ gy = reinterpret_cast<float4*>(out) +
      (size_t)blockIdx.x * XF4 + ((size_t)wv << 10);

  // ---- stage-in: 16 instrs, each a contiguous 1KB span (permuted within
  // 256B groups so the linear LDS dest realizes the swizzled layout).
#if USE_GLL
#pragma unroll
  for (int j = 0; j < 16; ++j) {
    const int s  = j * 64 + lane;          // linear LDS f4 this lane fills
    const int cc = s >> 4;
    const int q  = (s & 15) ^ (cc & 15);   // inverse swizzle on the source
    const float4* g = gx + cc * 16 + q;
    __builtin_amdgcn_global_load_lds(
        (const __attribute__((address_space(1))) void*)g,
        (__attribute__((address_space(3))) void*)&Lb[j * 64], 16, 0, 0);
  }
  asm volatile("s_waitcnt vmcnt(0)" ::: "memory");
  __builtin_amdgcn_sched_barrier(0);
#else
  {
    float4 tmp[16];
#pragma unroll
    for (int j = 0; j < 16; ++j) {
      const int s  = j * 64 + lane;
      const int cc = s >> 4;
      const int q  = (s & 15) ^ (cc & 15);
      tmp[j] = gx[cc * 16 + q];
    }
#pragma unroll
    for (int j = 0; j < 16; ++j) Lb[j * 64 + lane] = tmp[j];
    asm volatile("s_waitcnt lgkmcnt(0)" ::: "memory");
    __builtin_amdgcn_sched_barrier(0);
  }
#endif

  // ---- wave 0: Ms[d] = (A^L)^(2^d) in-register via __shfl (R10 code) ----
  if (t < 64) {
    const int r = t >> 3, c = t & 7;
    float p1[NS] = {0.f, 0.f, 0.f, 0.f};
    float p2[NS] = {0.f, 0.f, 0.f, 0.f};
    if (c & 1) p2[c >> 1] = 1.0f; else p1[c >> 1] = 1.0f;
    (void)step_cascade(0.0f, CO, p1, p2);
    float m = (r & 1) ? p2[r >> 1] : p1[r >> 1];
    for (int it = 0; it < LOG2L + LOG2P - 1; ++it) {
      float acc = 0.0f;
#pragma unroll
      for (int k = 0; k < NSTATE; ++k)
        acc = fmaf(__shfl(m, r * 8 + k), __shfl(m, k * 8 + c), acc);
      m = acc;
      if (it >= LOG2L - 1) Msf[(it - (LOG2L - 1)) * 64 + t] = m;
    }
  }

  // ---- phase 1: chunk final state from zero, reading LDS-resident x ----
  float s1[NS] = {0.f, 0.f, 0.f, 0.f};
  float s2[NS] = {0.f, 0.f, 0.f, 0.f};
#pragma unroll
  for (int q = 0; q < LQ; ++q)
    adv4(Lb[lane * 16 + (q ^ (lane & 15))], CO, s1, s2);

  float w[NSTATE];
#pragma unroll
  for (int k = 0; k < NS; ++k) { w[2 * k] = s1[k]; w[2 * k + 1] = s2[k]; }

  // ---- phase 2: Kogge-Stone affine scan (R10 code; W/Ms do not alias x) ----
  for (int d = 0; d < LOG2P; ++d) {
#pragma unroll
    for (int r = 0; r < NSTATE; ++r) Wf[t * 9 + r] = w[r];
    __syncthreads();  // also orders wave0's Ms writes before first use
    if (t >= (1 << d)) {
      const int src = (t - (1 << d)) * 9;
      float prev[NSTATE];
#pragma unroll
      for (int r = 0; r < NSTATE; ++r) prev[r] = Wf[src + r];
#pragma unroll
      for (int r = 0; r < NSTATE; ++r) {
        float acc = w[r];
#pragma unroll
        for (int k = 0; k < NSTATE; ++k)
          acc = fmaf(Msf[d * 64 + r * 8 + k], prev[k], acc);
        w[r] = acc;
      }
    }
    __syncthreads();
  }

  // ---- phase 3: exclusive shift -> s_init in registers ----
#pragma unroll
  for (int r = 0; r < NSTATE; ++r) Wf[t * 9 + r] = w[r];
  __syncthreads();
  {
    const int src = (t == 0 ? 0 : t - 1) * 9;
#pragma unroll
    for (int k = 0; k < NS; ++k) {
      s1[k] = (t == 0) ? 0.0f : Wf[src + 2 * k];
      s2[k] = (t == 0) ? 0.0f : Wf[src + 2 * k + 1];
    }
  }
  // no barrier needed: P4 touches only the x-region (disjoint from W/Ms)

  // ---- phase 4: replay from exact init, in-place y over x, dense out ----
#pragma unroll
  for (int q = 0; q < LQ; ++q) {
    const int s = lane * 16 + (q ^ (lane & 15));
    Lb[s] = out4(Lb[s], CO, s1, s2);  // own slots only
  }
  asm volatile("s_waitcnt lgkmcnt(0)" ::: "memory");  // wave's writes committed
  __builtin_amdgcn_sched_barrier(0);

#pragma unroll
  for (int h = 0; h < 2; ++h) {
    float4 tq[8];
#pragma unroll
    for (int j = 0; j < 8; ++j) {
      const int g  = (h * 8 + j) * 64 + lane;
      const int cc = g >> 4;
      tq[j] = Lb[cc * 16 + ((g & 15) ^ (cc & 15))];
    }
#pragma unroll
    for (int j = 0; j < 8; ++j) gy[(h * 8 + j) * 64 + lane] = tq[j];
  }
}

// ===========================================================================
// Fallback: R10's kernel, verbatim (42µs, clean counters).
__global__ __launch_bounds__(P) void k_fused(const float* __restrict__ x,
                                             const float* __restrict__ bc,
                                             const float* __restrict__ ac,
                                             float* __restrict__ out) {
  __shared__ float4 arena[4096];
  float* Msf = reinterpret_cast<float*>(arena);
  float* Wf  = reinterpret_cast<float*>(arena) + 576;

  const int t = threadIdx.x;
  float b0[NS], b1[NS], b2[NS], a1[NS], a2[NS];
  load_coefs(bc, ac, b0, b1, b2, a1, a2);

  if (t < 64) {
    const int r = t >> 3, c = t & 7;
    float p1[NS] = {0.f, 0.f, 0.f, 0.f};
    float p2[NS] = {0.f, 0.f, 0.f, 0.f};
    if (c & 1) p2[c >> 1] = 1.0f; else p1[c >> 1] = 1.0f;
    (void)step_cascade(0.0f, CO, p1, p2);
    float m = (r & 1) ? p2[r >> 1] : p1[r >> 1];
    for (int it = 0; it < LOG2L + LOG2P - 1; ++it) {
      float acc = 0.0f;
#pragma unroll
      for (int k = 0; k < NSTATE; ++k)
        acc = fmaf(__shfl(m, r * 8 + k), __shfl(m, k * 8 + c), acc);
      m = acc;
      if (it >= LOG2L - 1) Msf[(it - (LOG2L - 1)) * 64 + t] = m;
    }
  }

  const float4* __restrict__ gp =
      reinterpret_cast<const float4*>(x) + ((size_t)blockIdx.x * P + t) * LQ;
  float s1[NS] = {0.f, 0.f, 0.f, 0.f};
  float s2[NS] = {0.f, 0.f, 0.f, 0.f};
  float4 ld[4];
#pragma unroll
  for (int j = 0; j < 4; ++j) ld[j] = gp[j];
#pragma unroll
  for (int q0 = 0; q0 < LQ; q0 += 4) {
#pragma unroll
    for (int j = 0; j < 4; ++j) {
      const float4 u = ld[j];
      if (q0 + 4 + j < LQ) ld[j] = gp[q0 + 4 + j];
      adv4(u, CO, s1, s2);
    }
  }

  float w[NSTATE];
#pragma unroll
  for (int k = 0; k < NS; ++k) { w[2 * k] = s1[k]; w[2 * k + 1] = s2[k]; }

  for (int d = 0; d < LOG2P; ++d) {
#pragma unroll
    for (int r = 0; r < NSTATE; ++r) Wf[t * 9 + r] = w[r];
    __syncthreads();
    if (t >= (1 << d)) {
      const int src = (t - (1 << d)) * 9;
      float prev[NSTATE];
#pragma unroll
      for (int r = 0; r < NSTATE; ++r) prev[r] = Wf[src + r];
#pragma unroll
      for (int r = 0; r < NSTATE; ++r) {
        float acc = w[r];
#pragma unroll
        for (int k = 0; k < NSTATE; ++k)
          acc = fmaf(Msf[d * 64 + r * 8 + k], prev[k], acc);
        w[r] = acc;
      }
    }
    __syncthreads();
  }

#pragma unroll
  for (int r = 0; r < NSTATE; ++r) Wf[t * 9 + r] = w[r];
  __syncthreads();
  {
    const int src = (t == 0 ? 0 : t - 1) * 9;
#pragma unroll
    for (int k = 0; k < NS; ++k) {
      s1[k] = (t == 0) ? 0.0f : Wf[src + 2 * k];
      s2[k] = (t == 0) ? 0.0f : Wf[src + 2 * k + 1];
    }
  }
  __syncthreads();

  const int lane = t & 63;
  const int wv   = t >> 6;
  float4* __restrict__ Lb = arena + (wv << 9);
  float4* __restrict__ gout = reinterpret_cast<float4*>(out) +
      ((size_t)blockIdx.x * P + (wv << 6)) * LQ;

#pragma unroll
  for (int j = 0; j < 4; ++j) ld[j] = gp[j];

#pragma unroll
  for (int q = 0; q < 8; ++q) {
    const float4 u = ld[q & 3];
    ld[q & 3] = gp[q + 4];
    Lb[lane * 8 + (q ^ (lane & 7))] = out4(u, CO, s1, s2);
  }
  asm volatile("s_waitcnt lgkmcnt(0)" ::: "memory");
  __builtin_amdgcn_sched_barrier(0);
#pragma unroll
  for (int k = 0; k < 8; ++k) {
    const int s = k * 64 + lane;
    const int c = s >> 3, q = s & 7;
    gout[c * 16 + q] = Lb[c * 8 + (q ^ (c & 7))];
  }
  asm volatile("s_waitcnt lgkmcnt(0)" ::: "memory");
  __builtin_amdgcn_sched_barrier(0);

#pragma unroll
  for (int q = 8; q < 16; ++q) {
    const float4 u = ld[q & 3];
    if (q + 4 < 16) ld[q & 3] = gp[q + 4];
    Lb[lane * 8 + ((q & 7) ^ (lane & 7))] = out4(u, CO, s1, s2);
  }
  asm volatile("s_waitcnt lgkmcnt(0)" ::: "memory");
  __builtin_amdgcn_sched_barrier(0);
#pragma unroll
  for (int k = 0; k < 8; ++k) {
    const int s = k * 64 + lane;
    const int c = s >> 3, q = s & 7;
    gout[c * 16 + 8 + q] = Lb[c * 8 + (q ^ (c & 7))];
  }
}

extern "C" void kernel_launch(void* const* d_in, const int* in_sizes, int n_in,
                              void* d_out, int out_size, void* d_ws, size_t ws_size,
                              hipStream_t stream) {
  const float* x  = (const float*)d_in[0];  // (B, T, 1)
  const float* bc = (const float*)d_in[1];  // (NS, 3)
  const float* ac = (const float*)d_in[2];  // (NS, 2)
  float* out = (float*)d_out;               // (B, T, 1)

  // Opt in to >64KB dynamic LDS (gfx950: 160KB/CU). Deterministic each call.
  hipError_t arc = hipFuncSetAttribute(
      reinterpret_cast<const void*>(k_fused_res),
      hipFuncAttributeMaxDynamicSharedMemorySize, (int)DYN_LDS);

  bool ok = (arc == hipSuccess);
  if (ok) {
    k_fused_res<<<BATCH, P, DYN_LDS, stream>>>(x, bc, ac, out);
    if (hipGetLastError() != hipSuccess) ok = false;
  }
  if (!ok) {
    k_fused<<<BATCH, P, 0, stream>>>(x, bc, ac, out);
  }
}

// Round 13
// 41.476 us; speedup vs baseline: 2.1154x; 1.2312x over previous
//
#include <hip/hip_runtime.h>

// Fully-fused cascaded-biquad IIR (DF2T) via linear state-space chunking.
// R13 = R10 skeleton (64KB static arena, 2 blocks/CU, block = one batch row,
// 512 threads = 512 chunks) with ALL global reads done as 128B-dense
// global_load_lds staging (per-wave 8KB region, two half-tiles, wave-local
// vmcnt/lgkm sync). P4 computes in-place in LDS and stores out dense.
//   P1: stage HT -> compute chunk state from zero (x never touches VGPRs)
//   P2: Kogge-Stone affine scan (R10 code; Ms built in-reg during P1 loads)
//   P3: exclusive shift -> s_init in registers
//   P4: stage HT -> in-place replay -> dense store

namespace {
constexpr int NS     = 4;
constexpr int BATCH  = 512;
constexpr int TLEN   = 32768;      // 2^15
constexpr int NSTATE = 8;
constexpr int P      = 512;        // chunks per batch = threads per block
constexpr int L      = TLEN / P;   // 64 steps per chunk
constexpr int LQ     = L / 4;      // 16 float4 per chunk
constexpr int LOG2P  = 9;
constexpr int LOG2L  = 6;
constexpr int NSQ    = LOG2L + LOG2P - 1;  // 14 squaring iterations
}

#if defined(__has_builtin)
#  if __has_builtin(__builtin_amdgcn_global_load_lds)
#    define USE_GLL 1
#  endif
#endif
#ifndef USE_GLL
#  define USE_GLL 0
#endif

#define WAIT_VM0 do { asm volatile("s_waitcnt vmcnt(0)" ::: "memory"); \
                      __builtin_amdgcn_sched_barrier(0); } while (0)
#define WAIT_LGKM0 do { asm volatile("s_waitcnt lgkmcnt(0)" ::: "memory"); \
                        __builtin_amdgcn_sched_barrier(0); } while (0)

__device__ __forceinline__ void load_coefs(const float* __restrict__ bc,
                                           const float* __restrict__ ac,
                                           float b0[NS], float b1[NS], float b2[NS],
                                           float a1[NS], float a2[NS]) {
#pragma unroll
  for (int k = 0; k < NS; ++k) {
    b0[k] = bc[3 * k];
    b1[k] = bc[3 * k + 1];
    b2[k] = bc[3 * k + 2];
    a1[k] = ac[2 * k];
    a2[k] = ac[2 * k + 1];
  }
}

// One time-step through the 4-section cascade (matches reference exactly).
__device__ __forceinline__ float step_cascade(float sig,
                                              const float b0[NS], const float b1[NS],
                                              const float b2[NS], const float a1[NS],
                                              const float a2[NS],
                                              float s1[NS], float s2[NS]) {
#pragma unroll
  for (int k = 0; k < NS; ++k) {
    float y = fmaf(b0[k], sig, s1[k]);
    s1[k]   = fmaf(-a1[k], y, fmaf(b1[k], sig, s2[k]));
    s2[k]   = fmaf(-a2[k], y, b2[k] * sig);
    sig = y;
  }
  return sig;
}

#define CO b0, b1, b2, a1, a2

__device__ __forceinline__ void adv4(const float4 u,
                                     const float b0[NS], const float b1[NS],
                                     const float b2[NS], const float a1[NS],
                                     const float a2[NS], float s1[NS], float s2[NS]) {
  (void)step_cascade(u.x, CO, s1, s2);
  (void)step_cascade(u.y, CO, s1, s2);
  (void)step_cascade(u.z, CO, s1, s2);
  (void)step_cascade(u.w, CO, s1, s2);
}

__device__ __forceinline__ float4 out4(const float4 u,
                                       const float b0[NS], const float b1[NS],
                                       const float b2[NS], const float a1[NS],
                                       const float a2[NS], float s1[NS], float s2[NS]) {
  float4 y;
  y.x = step_cascade(u.x, CO, s1, s2);
  y.y = step_cascade(u.y, CO, s1, s2);
  y.z = step_cascade(u.z, CO, s1, s2);
  y.w = step_cascade(u.w, CO, s1, s2);
  return y;
}

// Stage one half-tile (64 chunks x 8 f4 = 8KB) of this wave's chunk data:
// linear LDS dest, per-lane pre-swizzled global source (rule 21, R12-valid).
// Instr j: lanes cover 8 chunks' full 128B lines -> dense.
__device__ __forceinline__ void stage_ht(const float4* __restrict__ gx_w,
                                         float4* R, int lane, int ht) {
#if USE_GLL
#pragma unroll
  for (int j = 0; j < 8; ++j) {
    const int cc = j * 8 + (lane >> 3);
    const int qq = lane & 7;
    const float4* g = gx_w + cc * 16 + ht * 8 + (qq ^ (cc & 7));
    __builtin_amdgcn_global_load_lds(
        (const __attribute__((address_space(1))) void*)g,
        (__attribute__((address_space(3))) void*)&R[j * 64], 16, 0, 0);
  }
#else
#pragma unroll
  for (int j = 0; j < 8; ++j) {
    const int cc = j * 8 + (lane >> 3);
    const int qq = lane & 7;
    R[j * 64 + lane] = gx_w[cc * 16 + ht * 8 + (qq ^ (cc & 7))];
  }
#endif
}

__global__ __launch_bounds__(P) void k_fused(const float* __restrict__ x,
                                             const float* __restrict__ bc,
                                             const float* __restrict__ ac,
                                             float* __restrict__ out) {
  // 64 KiB arena. P1/P4: wave wv owns f4 [wv*512, wv*512+512) (8KB).
  // Scan: Msf = floats [0,576), Wf = floats [576,5184) — aliases wave regions,
  // phases separated by block barriers; Ms stored only after P1 barrier.
  __shared__ float4 arena[4096];
  float* Msf = reinterpret_cast<float*>(arena);
  float* Wf  = reinterpret_cast<float*>(arena) + 576;

  const int t    = threadIdx.x;
  const int lane = t & 63;
  const int wv   = t >> 6;
  const int swz  = lane & 7;
  float4* __restrict__ R = arena + (wv << 9);

  float b0[NS], b1[NS], b2[NS], a1[NS], a2[NS];
  load_coefs(bc, ac, b0, b1, b2, a1, a2);

  const float4* __restrict__ gx_w = reinterpret_cast<const float4*>(x) +
      (size_t)blockIdx.x * (P * LQ) + ((size_t)wv << 10);  // wave's 64 chunks
  float4* __restrict__ gy_w = reinterpret_cast<float4*>(out) +
      (size_t)blockIdx.x * (P * LQ) + ((size_t)wv << 10);

  // ---- P1 HT0 staging (issued immediately; HBM latency hides under Ms) ----
  stage_ht(gx_w, R, lane, 0);

  // ---- Ms squarings in-register (wave 0 only), stored AFTER P1 barrier ----
  float mpow[9];
#pragma unroll
  for (int i = 0; i < 9; ++i) mpow[i] = 0.0f;
  if (t < 64) {
    const int r = lane >> 3, c = lane & 7;
    float p1[NS] = {0.f, 0.f, 0.f, 0.f};
    float p2[NS] = {0.f, 0.f, 0.f, 0.f};
    if (c & 1) p2[c >> 1] = 1.0f; else p1[c >> 1] = 1.0f;
    (void)step_cascade(0.0f, CO, p1, p2);
    float m = (r & 1) ? p2[r >> 1] : p1[r >> 1];  // A element (r,c)
#pragma unroll
    for (int it = 0; it < NSQ; ++it) {
      float acc = 0.0f;
#pragma unroll
      for (int k = 0; k < NSTATE; ++k)
        acc = fmaf(__shfl(m, r * 8 + k), __shfl(m, k * 8 + c), acc);
      m = acc;
      if (it >= LOG2L - 1) mpow[it - (LOG2L - 1)] = m;
    }
  }

  // ---- P1: compute chunk state from zero, half-tile at a time ----
  float s1[NS] = {0.f, 0.f, 0.f, 0.f};
  float s2[NS] = {0.f, 0.f, 0.f, 0.f};
  WAIT_VM0;
#pragma unroll
  for (int q = 0; q < 8; ++q) adv4(R[lane * 8 + (q ^ swz)], CO, s1, s2);
  WAIT_LGKM0;  // WAR: ds_reads done before HT1 overwrites the region
  stage_ht(gx_w, R, lane, 1);
  WAIT_VM0;
#pragma unroll
  for (int q = 0; q < 8; ++q) adv4(R[lane * 8 + (q ^ swz)], CO, s1, s2);

  float w[NSTATE];
#pragma unroll
  for (int k = 0; k < NS; ++k) { w[2 * k] = s1[k]; w[2 * k + 1] = s2[k]; }

  __syncthreads();  // all P1 LDS traffic done; arena repurposed for scan
  if (t < 64) {
#pragma unroll
    for (int d = 0; d < LOG2P; ++d) Msf[d * 64 + t] = mpow[d];
  }

  // ---- P2: Kogge-Stone affine scan (R10 code) ----
  for (int d = 0; d < LOG2P; ++d) {
#pragma unroll
    for (int r = 0; r < NSTATE; ++r) Wf[t * 9 + r] = w[r];
    __syncthreads();  // d=0: also orders Ms stores before first Ms read
    if (t >= (1 << d)) {
      const int src = (t - (1 << d)) * 9;
      float prev[NSTATE];
#pragma unroll
      for (int r = 0; r < NSTATE; ++r) prev[r] = Wf[src + r];
#pragma unroll
      for (int r = 0; r < NSTATE; ++r) {
        float acc = w[r];
#pragma unroll
        for (int k = 0; k < NSTATE; ++k)
          acc = fmaf(Msf[d * 64 + r * 8 + k], prev[k], acc);  // uniform: broadcast
        w[r] = acc;
      }
    }
    __syncthreads();
  }

  // ---- P3: exclusive shift -> s_init in registers ----
#pragma unroll
  for (int r = 0; r < NSTATE; ++r) Wf[t * 9 + r] = w[r];
  __syncthreads();
  {
    const int src = (t == 0 ? 0 : t - 1) * 9;
#pragma unroll
    for (int k = 0; k < NS; ++k) {
      s1[k] = (t == 0) ? 0.0f : Wf[src + 2 * k];
      s2[k] = (t == 0) ? 0.0f : Wf[src + 2 * k + 1];
    }
  }
  __syncthreads();  // scan reads done before P4 staging overwrites arena

  // ---- P4: replay from exact init, half-tile at a time, dense out ----
#pragma unroll
  for (int ht = 0; ht < 2; ++ht) {
    stage_ht(gx_w, R, lane, ht);
    WAIT_VM0;
#pragma unroll
    for (int q = 0; q < 8; ++q) {
      const int s = lane * 8 + (q ^ swz);
      R[s] = out4(R[s], CO, s1, s2);  // in-place: own slots only
    }
    WAIT_LGKM0;  // in-place writes committed before transpose-out reads
#pragma unroll
    for (int j = 0; j < 8; ++j) {
      const int cc = j * 8 + (lane >> 3);
      const int qq = lane & 7;
      const float4 v = R[j * 64 + lane];
      gy_w[cc * 16 + ht * 8 + (qq ^ (cc & 7))] = v;  // dense 128B lines
    }
    if (ht == 0) WAIT_LGKM0;  // WAR: store-side ds_reads done before HT1 staging
  }
}

extern "C" void kernel_launch(void* const* d_in, const int* in_sizes, int n_in,
                              void* d_out, int out_size, void* d_ws, size_t ws_size,
                              hipStream_t stream) {
  const float* x  = (const float*)d_in[0];  // (B, T, 1)
  const float* bc = (const float*)d_in[1];  // (NS, 3)
  const float* ac = (const float*)d_in[2];  // (NS, 2)
  float* out = (float*)d_out;               // (B, T, 1)

  k_fused<<<BATCH, P, 0, stream>>>(x, bc, ac, out);
}